// Round 16
// baseline (137.222 us; speedup 1.0000x reference)
//
#include <hip/hip_runtime.h>

#define NN 50000
#define NNP 50176        // NN padded to 196*256
#define NE 1000000
#define NBK 196          // dst buckets of 256 nodes
#define ESTRIDE 5632     // es2 bucket capacity: mean 5102, sigma ~71 -> +7.4 sigma
#define EPC 2048         // edges per place chunk (512 thr x 4)
#define NCH 489          // ceil(NE/EPC); last chunk = 576 edges (%4==0)

// fallback-path defs
#define EPB 1024
#define PB 977

// ================= place4: h0-init + VECTOR loads + MLP + bucket-group =====
// 489 blocks x 512 threads. At 512 thr the VGPR cap is 128 (R10/R11's spills
// were at 1024 thr / 64-VGPR cap) -> the 4-edge register set (~50 live regs)
// now fits. Inputs: 3x float4 (ea) + int4 (src) + int4 (dst) per thread,
// replacing 20 scalar 12B-stride loads. Sequential per-edge MLP; LDS
// counting-sort by dst bucket; linear streaming write.
__global__ __launch_bounds__(512)
void place4(const float* __restrict__ x,
            const float* __restrict__ ea,
            const int* __restrict__ src,
            const int* __restrict__ dst,
            const float* __restrict__ w1,
            const float* __restrict__ b1,
            const float* __restrict__ w2,
            const float* __restrict__ b2,
            uint2* __restrict__ es,
            int* __restrict__ ebase,
            float* __restrict__ hA) {
    __shared__ float sw1[192];
    __shared__ float sb1[64];
    __shared__ float sw2[64];
    __shared__ int hist[NBK];
    __shared__ int part[256];
    __shared__ int lexcl[NBK];
    __shared__ __align__(16) uint2 eLDS[EPC];   // 16 KB
    const int t = threadIdx.x;
    const int j = blockIdx.x;
    if (t < 192) sw1[t] = w1[t];
    if (t < 64) { sb1[t] = b1[t]; sw2[t] = w2[t]; }
    if (t < NBK) hist[t] = 0;
    {   // h0 init folded in (blocks 0..97 cover all nodes)
        int i = j * 512 + t;
        if (i < NN) hA[i] = x[5 * i + 2];
    }
    __syncthreads();
    const float bz = b2[0];
    const int e0 = j * EPC;
    const int myN = (NE - e0 < EPC) ? (NE - e0) : EPC;   // multiple of 4
    const bool act = (4 * t < myN);

    // ---- vector loads: 3 float4 + 2 int4 per thread (edges 4t..4t+3) ----
    int dd[4], ss[4];
    float ax[4], ay[4], az[4];
    if (act) {
        const float4* eav = (const float4*)(ea + 3 * (size_t)e0);
        float4 A0 = eav[3 * t + 0];
        float4 A1 = eav[3 * t + 1];
        float4 A2 = eav[3 * t + 2];
        int4 s4 = ((const int4*)(src + e0))[t];
        int4 d4 = ((const int4*)(dst + e0))[t];
        ax[0] = A0.x; ay[0] = A0.y; az[0] = A0.z;
        ax[1] = A0.w; ay[1] = A1.x; az[1] = A1.y;
        ax[2] = A1.z; ay[2] = A1.w; az[2] = A2.x;
        ax[3] = A2.y; ay[3] = A2.z; az[3] = A2.w;
        dd[0] = d4.x; dd[1] = d4.y; dd[2] = d4.z; dd[3] = d4.w;
        ss[0] = s4.x; ss[1] = s4.y; ss[2] = s4.z; ss[3] = s4.w;
    } else {
        dd[0] = dd[1] = dd[2] = dd[3] = -1;
        ss[0] = ss[1] = ss[2] = ss[3] = 0;
        ax[0] = ax[1] = ax[2] = ax[3] = 0.f;
        ay[0] = ay[1] = ay[2] = ay[3] = 0.f;
        az[0] = az[1] = az[2] = az[3] = 0.f;
    }

    // ---- sequential per-edge MLP (small transient live set) ----
    float ce[4]; int rr[4];
#pragma unroll
    for (int k = 0; k < 4; ++k) {
        if (dd[k] >= 0) {
            float a0 = ax[k], a1 = ay[k], a2 = az[k];
            float c0 = bz, c1 = 0.f, c2 = 0.f, c3 = 0.f;
#pragma unroll
            for (int kk = 0; kk < 64; kk += 4) {
                float h0 = fmaf(a0, sw1[kk+0], fmaf(a1, sw1[64+kk+0], fmaf(a2, sw1[128+kk+0], sb1[kk+0])));
                float h1 = fmaf(a0, sw1[kk+1], fmaf(a1, sw1[64+kk+1], fmaf(a2, sw1[128+kk+1], sb1[kk+1])));
                float h2 = fmaf(a0, sw1[kk+2], fmaf(a1, sw1[64+kk+2], fmaf(a2, sw1[128+kk+2], sb1[kk+2])));
                float h3 = fmaf(a0, sw1[kk+3], fmaf(a1, sw1[64+kk+3], fmaf(a2, sw1[128+kk+3], sb1[kk+3])));
                c0 = fmaf(fmaxf(h0, 0.f), sw2[kk+0], c0);
                c1 = fmaf(fmaxf(h1, 0.f), sw2[kk+1], c1);
                c2 = fmaf(fmaxf(h2, 0.f), sw2[kk+2], c2);
                c3 = fmaf(fmaxf(h3, 0.f), sw2[kk+3], c3);
            }
            ce[k] = (c0 + c1) + (c2 + c3);
            rr[k] = atomicAdd(&hist[dd[k] >> 8], 1);
        }
    }
    __syncthreads();
    // exclusive scan of hist over 196 buckets (threads 0..255, all barrier)
    int val = 0;
    if (t < 256) { val = (t < NBK) ? hist[t] : 0; part[t] = val; }
    __syncthreads();
    for (int off = 1; off < 256; off <<= 1) {
        int xv = 0, add = 0;
        if (t < 256) { xv = part[t]; if (t >= off) add = part[t - off]; }
        __syncthreads();
        if (t < 256) part[t] = xv + add;
        __syncthreads();
    }
    if (t < NBK) {
        int excl = part[t] - val;
        lexcl[t] = excl;
        ebase[j * NBK + t] = (excl << 16) | val;   // both <= 2048 < 65536
    }
    __syncthreads();
#pragma unroll
    for (int k = 0; k < 4; ++k) {
        if (dd[k] >= 0) {
            int d = dd[k];
            int pos = lexcl[d >> 8] + rr[k];       // dense in [0, myN)
            eLDS[pos] = make_uint2((unsigned)ss[k] | ((unsigned)(d & 255) << 17),
                                   __float_as_uint(ce[k]));
        }
    }
    __syncthreads();
    for (int p = t; p < myN; p += 512)             // linear streaming write
        es[e0 + p] = eLDS[p];
}

// ================= sortround1: gather + dst-sort + round 1 (R15-proven) ====
__global__ __launch_bounds__(1024)
void sortround1(const int* __restrict__ ebase,
                const uint2* __restrict__ es,
                uint2* __restrict__ es2,
                uint2* __restrict__ nodePtr,
                const float* __restrict__ hold,
                float* __restrict__ hnew,
                const float* __restrict__ root,
                const float* __restrict__ bias) {
    __shared__ int cbase[NCH + 1];   // exclusive scan of per-chunk run lens
    __shared__ int cex[NCH];         // run offset within each chunk
    __shared__ int hist[256];
    __shared__ int partc[512];       // chunk-scan workspace (489 -> 512)
    __shared__ int part[256];
    __shared__ int cur[256];
    __shared__ float lagg[256];
    const int t = threadIdx.x;
    const int b = blockIdx.x;
    if (t < 256) { hist[t] = 0; lagg[t] = 0.f; }
    // load (excl,cnt) column and scan cnt over 489 chunks
    int c = 0;
    if (t < NCH) {
        int pk = ebase[t * NBK + b];
        cex[t] = pk >> 16;
        c = pk & 0xFFFF;
    }
    if (t < 512) partc[t] = (t < NCH) ? c : 0;
    __syncthreads();
    for (int off = 1; off < 512; off <<= 1) {
        int xv = 0, add = 0;
        if (t < 512) { xv = partc[t]; if (t >= off) add = partc[t - off]; }
        __syncthreads();
        if (t < 512) partc[t] = xv + add;
        __syncthreads();
    }
    if (t < NCH) cbase[t] = partc[t] - c;
    if (t == 0) cbase[NCH] = partc[NCH - 1];       // total C
    __syncthreads();
    const int C = cbase[NCH];                      // <= ~5400; reg slots 6144

    // flat gather into registers + EARLY h-gather (overlaps the scans below)
    uint2 v[6]; float hv[6]; bool m[6];
#pragma unroll
    for (int k = 0; k < 6; ++k) {
        int p = k * 1024 + t;
        m[k] = (p < C);
        if (m[k]) {
            int lo = 0, hi = NCH - 1;              // largest j: cbase[j] <= p
            while (lo < hi) { int mid = (lo + hi + 1) >> 1; if (cbase[mid] <= p) lo = mid; else hi = mid - 1; }
            v[k] = es[lo * EPC + cex[lo] + (p - cbase[lo])];
            atomicAdd(&hist[(v[k].x >> 17) & 255], 1);
            hv[k] = hold[v[k].x & 0x1FFFF];
        }
    }
    __syncthreads();
    // scan hist over 256 node-slots
    int val = 0;
    if (t < 256) { val = hist[t]; part[t] = val; }
    __syncthreads();
    for (int off = 1; off < 256; off <<= 1) {
        int xv = 0, add = 0;
        if (t < 256) { xv = part[t]; if (t >= off) add = part[t - off]; }
        __syncthreads();
        if (t < 256) part[t] = xv + add;
        __syncthreads();
    }
    if (t < 256) {
        int excl = part[t] - val;
        cur[t] = excl;
        int ec = (excl < ESTRIDE) ? excl : ESTRIDE;
        nodePtr[b * 256 + t] = make_uint2((unsigned)(b * ESTRIDE + ec), (unsigned)val);
    }
    __syncthreads();
    // scatter to es2 + round-1 accumulate (h values already in registers)
#pragma unroll
    for (int k = 0; k < 6; ++k) {
        if (m[k]) {
            int key = (v[k].x >> 17) & 255;
            int pos = atomicAdd(&cur[key], 1);
            if (pos < ESTRIDE) es2[b * ESTRIDE + pos] = v[k];
            atomicAdd(&lagg[key], hv[k] * __uint_as_float(v[k].y));
        }
    }
    __syncthreads();
    if (t < 256) {
        int node = b * 256 + t;
        if (node < NN) {
            float inv = (val > 0) ? (1.0f / (float)val) : 0.f;
            hnew[node] = fmaxf(fmaf(hold[node], root[0], fmaf(lagg[t], inv, bias[0])), 0.f);
        }
    }
}

// ================= round_csr: vector-CSR, 8 lanes/row, batched (R15) =======
__global__ __launch_bounds__(256)
void round_csr(const uint2* __restrict__ nodePtr,
               const uint2* __restrict__ es2,
               const float* __restrict__ hold,
               float* __restrict__ hnew,
               const float* __restrict__ root,
               const float* __restrict__ bias) {
    int g = blockIdx.x * 256 + threadIdx.x;
    int row = g >> 3;
    int sub = g & 7;
    uint2 pk = nodePtr[row];
    int beg = (int)pk.x;
    int len = (int)pk.y;
    bool m0 = (sub      < len), m1 = (sub + 8  < len);
    bool m2 = (sub + 16 < len), m3 = (sub + 24 < len);
    uint2 v0, v1, v2, v3;
    if (m0) v0 = es2[beg + sub];
    if (m1) v1 = es2[beg + sub + 8];
    if (m2) v2 = es2[beg + sub + 16];
    if (m3) v3 = es2[beg + sub + 24];
    float g0 = 0.f, g1 = 0.f, g2 = 0.f, g3 = 0.f;
    if (m0) g0 = hold[v0.x & 0x1FFFF];
    if (m1) g1 = hold[v1.x & 0x1FFFF];
    if (m2) g2 = hold[v2.x & 0x1FFFF];
    if (m3) g3 = hold[v3.x & 0x1FFFF];
    float acc = 0.f;
    if (m0) acc += g0 * __uint_as_float(v0.y);
    if (m1) acc += g1 * __uint_as_float(v1.y);
    if (m2) acc += g2 * __uint_as_float(v2.y);
    if (m3) acc += g3 * __uint_as_float(v3.y);
    for (int k = sub + 32; k < len; k += 8) {      // rare (deg>32: ~0.4%)
        uint2 v = es2[beg + k];
        acc += hold[v.x & 0x1FFFF] * __uint_as_float(v.y);
    }
    acc += __shfl_xor(acc, 1);
    acc += __shfl_xor(acc, 2);
    acc += __shfl_xor(acc, 4);
    if (sub == 0 && row < NN) {
        float inv = (len > 0) ? (1.0f / (float)len) : 0.f;
        hnew[row] = fmaxf(fmaf(hold[row], root[0], fmaf(acc, inv, bias[0])), 0.f);
    }
}

// ================= fallback-path kernels (ws too small) ====================
__global__ void bucket_count(const int* __restrict__ dst, int* __restrict__ bcnt,
                             const float* __restrict__ x, float* __restrict__ h) {
    __shared__ int hist[NBK];
    int t = threadIdx.x;
    if (t < NBK) hist[t] = 0;
    __syncthreads();
    int gid = blockIdx.x * 256 + t;
    if (gid < NN) h[gid] = x[5 * gid + 2];
#pragma unroll
    for (int j = 0; j < 4; ++j) {
        int e = blockIdx.x * EPB + j * 256 + t;
        if (e < NE) atomicAdd(&hist[dst[e] >> 8], 1);
    }
    __syncthreads();
    if (t < NBK && hist[t]) atomicAdd(&bcnt[t], hist[t]);
}

__global__ void bucket_scan(const int* __restrict__ bcnt,
                            int* __restrict__ sBeg,
                            int* __restrict__ cursor,
                            int* __restrict__ sLim) {
    __shared__ int part[256];
    int t = threadIdx.x;
    int v = (t < NBK) ? ((bcnt[t] + 1) & ~1) : 0;   // round up to even
    part[t] = v;
    __syncthreads();
    for (int off = 1; off < 256; off <<= 1) {
        int x = part[t];
        int add = (t >= off) ? part[t - off] : 0;
        __syncthreads();
        part[t] = x + add;
        __syncthreads();
    }
    if (t < NBK) {
        int excl = part[t] - v;
        sBeg[t] = excl;
        cursor[t] = excl;
        sLim[t] = 0x7FFFFFFF;   // exact counts: overflow impossible
    }
}

__global__ void place_kernel(const float* __restrict__ ea,
                             const int* __restrict__ src,
                             const int* __restrict__ dst,
                             const float* __restrict__ w1,
                             const float* __restrict__ b1,
                             const float* __restrict__ w2,
                             const float* __restrict__ b2,
                             const int* __restrict__ sLim,
                             int* __restrict__ cursor,
                             uint2* __restrict__ es,
                             int dumpbase) {
    __shared__ float sw1[192];
    __shared__ float sb1[64];
    __shared__ float sw2[64];
    __shared__ float sce[EPB];
    __shared__ int hist[NBK];
    __shared__ int hbase[NBK];
    int t = threadIdx.x;
    if (t < 192) sw1[t] = w1[t];
    if (t < 64) { sb1[t] = b1[t]; sw2[t] = w2[t]; }
    if (t < NBK) hist[t] = 0;
    __syncthreads();

    int r[4], dd[4];
#pragma unroll
    for (int j = 0; j < 4; ++j) {
        int e = blockIdx.x * EPB + j * 256 + t;
        dd[j] = -1;
        if (e < NE) {
            float a0 = ea[3 * e + 0];
            float a1 = ea[3 * e + 1];
            float a2 = ea[3 * e + 2];
            float c0 = b2[0], c1 = 0.f, c2 = 0.f, c3 = 0.f;
#pragma unroll
            for (int k = 0; k < 64; k += 4) {
                float h0 = fmaf(a0, sw1[k+0], fmaf(a1, sw1[64+k+0], fmaf(a2, sw1[128+k+0], sb1[k+0])));
                float h1 = fmaf(a0, sw1[k+1], fmaf(a1, sw1[64+k+1], fmaf(a2, sw1[128+k+1], sb1[k+1])));
                float h2 = fmaf(a0, sw1[k+2], fmaf(a1, sw1[64+k+2], fmaf(a2, sw1[128+k+2], sb1[k+2])));
                float h3 = fmaf(a0, sw1[k+3], fmaf(a1, sw1[64+k+3], fmaf(a2, sw1[128+k+3], sb1[k+3])));
                c0 = fmaf(fmaxf(h0, 0.f), sw2[k+0], c0);
                c1 = fmaf(fmaxf(h1, 0.f), sw2[k+1], c1);
                c2 = fmaf(fmaxf(h2, 0.f), sw2[k+2], c2);
                c3 = fmaf(fmaxf(h3, 0.f), sw2[k+3], c3);
            }
            sce[j * 256 + t] = (c0 + c1) + (c2 + c3);
            int d = dst[e];
            dd[j] = d;
            r[j] = atomicAdd(&hist[d >> 8], 1);
        }
    }
    __syncthreads();
    if (t < NBK) { int hv = hist[t]; if (hv) hbase[t] = atomicAdd(&cursor[t], hv); }
    __syncthreads();
#pragma unroll
    for (int j = 0; j < 4; ++j) {
        int e = blockIdx.x * EPB + j * 256 + t;
        if (e < NE) {
            int d = dd[j];
            int b = d >> 8;
            int pos = hbase[b] + r[j];
            if (pos >= sLim[b]) pos = dumpbase + (t & 63);
            unsigned pack = (unsigned)src[e] | ((unsigned)(d & 255) << 17);
            es[pos] = make_uint2(pack, __float_as_uint(sce[j * 256 + t]));
        }
    }
}

template<int FIRST>
__global__ __launch_bounds__(1024)
void round_fused_fb(const int* __restrict__ sBeg,
                    const int* __restrict__ sEnd,
                    const int* __restrict__ sLim,
                    const uint2* __restrict__ es,
                    const float* __restrict__ hold,
                    float* __restrict__ hnew,
                    float* __restrict__ invdeg,
                    const float* __restrict__ root,
                    const float* __restrict__ bias) {
    __shared__ float lagg[256];
    __shared__ int ldeg[256];
    int t = threadIdx.x;
    int b = blockIdx.x;
    if (t < 256) { lagg[t] = 0.f; if (FIRST) ldeg[t] = 0; }
    __syncthreads();
    int s0 = sBeg[b];
    int s1 = sEnd[b];
    { int cap = sLim[b]; if (s1 > cap) s1 = cap; }
    const uint4* es4 = (const uint4*)es;
    for (int p = s0 + t * 2; p < s1; p += 2048) {
        uint4 v = es4[p >> 1];
        {
            int sidx = v.x & 0x1FFFF;
            int dl = (v.x >> 17) & 255;
            atomicAdd(&lagg[dl], hold[sidx] * __uint_as_float(v.y));
            if (FIRST) atomicAdd(&ldeg[dl], 1);
        }
        if (p + 1 < s1) {
            int sidx = v.z & 0x1FFFF;
            int dl = (v.z >> 17) & 255;
            atomicAdd(&lagg[dl], hold[sidx] * __uint_as_float(v.w));
            if (FIRST) atomicAdd(&ldeg[dl], 1);
        }
    }
    __syncthreads();
    if (t < 256) {
        int node = b * 256 + t;
        if (node < NN) {
            float inv;
            if (FIRST) {
                int d = ldeg[t];
                inv = (d > 0) ? (1.0f / (float)d) : 0.f;
                invdeg[node] = inv;
            } else {
                inv = invdeg[node];
            }
            hnew[node] = fmaxf(fmaf(hold[node], root[0], fmaf(lagg[t], inv, bias[0])), 0.f);
        }
    }
}

// ================= launch =================

extern "C" void kernel_launch(void* const* d_in, const int* in_sizes, int n_in,
                              void* d_out, int out_size, void* d_ws, size_t ws_size,
                              hipStream_t stream) {
    const float* x    = (const float*)d_in[0];
    const int*   ei   = (const int*)d_in[1];
    const float* ea   = (const float*)d_in[2];
    const float* w1   = (const float*)d_in[3];
    const float* b1   = (const float*)d_in[4];
    const float* w2   = (const float*)d_in[5];
    const float* b2   = (const float*)d_in[6];
    const float* root = (const float*)d_in[7];
    const float* bias = (const float*)d_in[8];

    const int* src = ei;
    const int* dst = ei + NE;
    float* out = (float*)d_out;

    const size_t esN  = (size_t)NCH * EPC;                // chunked es (dense)
    const size_t es2N = (size_t)NBK * ESTRIDE + 64;       // sorted es2 + dump
    const size_t needFixed = esN * 8 + es2N * 8
                           + (size_t)(NCH * NBK) * 4      // ebase
                           + (size_t)NNP * 8              // nodePtr
                           + (size_t)NN * 4 * 2;          // hA, hB

    if (ws_size >= needFixed) {
        // -------- fixed path: 5 dispatches, no memset --------
        uint2* es      = (uint2*)d_ws;
        uint2* es2     = es + esN;
        int*   ebase   = (int*)(es2 + es2N);
        uint2* nodePtr = (uint2*)(ebase + (size_t)NCH * NBK);
        float* hA      = (float*)(nodePtr + NNP);
        float* hB      = hA + NN;

        place4<<<NCH, 512, 0, stream>>>(x, ea, src, dst, w1, b1, w2, b2,
                                        es, ebase, hA);
        sortround1<<<NBK, 1024, 0, stream>>>(ebase, es, es2, nodePtr,
                                             hA, hB, root, bias);
        const int gR = NNP * 8 / 256;    // 1568 blocks, 8 lanes/row
        round_csr<<<gR, 256, 0, stream>>>(nodePtr, es2, hB, hA, root, bias);
        round_csr<<<gR, 256, 0, stream>>>(nodePtr, es2, hA, hB, root, bias);
        round_csr<<<gR, 256, 0, stream>>>(nodePtr, es2, hB, out, root, bias);
    } else {
        // -------- fallback: exact counts via count+scan --------
        uint2* es     = (uint2*)d_ws;                    // NE + NBK entries
        int*   bcnt   = (int*)(es + NE + NBK);
        int*   cursor = bcnt + NBK;
        int*   sBeg   = cursor + NBK;
        int*   sLim   = sBeg + NBK;
        float* invdeg = (float*)(sLim + NBK);
        float* hB     = invdeg + NN;
        float* h      = out;

        hipMemsetAsync(bcnt, 0, NBK * 4, stream);
        bucket_count<<<PB, 256, 0, stream>>>(dst, bcnt, x, h);
        bucket_scan<<<1, 256, 0, stream>>>(bcnt, sBeg, cursor, sLim);
        place_kernel<<<PB, 256, 0, stream>>>(ea, src, dst, w1, b1, w2, b2,
                                             sLim, cursor, es, 0);
        round_fused_fb<1><<<NBK, 1024, 0, stream>>>(sBeg, cursor, sLim, es, h,  hB, invdeg, root, bias);
        round_fused_fb<0><<<NBK, 1024, 0, stream>>>(sBeg, cursor, sLim, es, hB, h,  invdeg, root, bias);
        round_fused_fb<0><<<NBK, 1024, 0, stream>>>(sBeg, cursor, sLim, es, h,  hB, invdeg, root, bias);
        round_fused_fb<0><<<NBK, 1024, 0, stream>>>(sBeg, cursor, sLim, es, hB, h,  invdeg, root, bias);
    }
}

// Round 17
// 134.240 us; speedup vs baseline: 1.0222x; 1.0222x over previous
//
#include <hip/hip_runtime.h>

#define NN 50000
#define NNP 50176        // NN padded to 196*256
#define NE 1000000
#define NBK 196          // dst buckets of 256 nodes
#define ESTRIDE 5632     // es2 bucket capacity: mean 5102, sigma ~71 -> +7.4 sigma
#define EPC 2048         // edges per place chunk (512 thr x 4)
#define NCH 489          // ceil(NE/EPC); last chunk = 576 edges

// fallback-path defs
#define EPB 1024
#define PB 977

// ================= place4: h0-init + MLP + chunk-local bucket-grouped write
// 489 blocks x 512 threads: ~1.9 blocks/CU so no idle CUs, finer tail, and
// the 512-thr launch bound doubles the VGPR cap to 128 (R10/R11: at 1024 thr
// the 64-VGPR cap spilled every multi-edge register-cached variant).
// Scalar loads + streaming per-edge MLP (proven; R16 showed vector loads are
// null - TLP already hides them); LDS counting-sort by dst bucket; ONE
// linear streaming write. ebase[j*196+b]=(excl<<16)|cnt.
__global__ __launch_bounds__(512)
void place4(const float* __restrict__ x,
            const float* __restrict__ ea,
            const int* __restrict__ src,
            const int* __restrict__ dst,
            const float* __restrict__ w1,
            const float* __restrict__ b1,
            const float* __restrict__ w2,
            const float* __restrict__ b2,
            uint2* __restrict__ es,
            int* __restrict__ ebase,
            float* __restrict__ hA) {
    __shared__ float sw1[192];
    __shared__ float sb1[64];
    __shared__ float sw2[64];
    __shared__ int hist[NBK];
    __shared__ int part[256];
    __shared__ int lexcl[NBK];
    __shared__ uint2 eLDS[EPC];        // 16 KB
    const int t = threadIdx.x;
    const int j = blockIdx.x;
    if (t < 192) sw1[t] = w1[t];
    if (t < 64) { sb1[t] = b1[t]; sw2[t] = w2[t]; }
    if (t < NBK) hist[t] = 0;
    {   // h0 init folded in (blocks 0..97 cover all nodes)
        int i = j * 512 + t;
        if (i < NN) hA[i] = x[5 * i + 2];
    }
    __syncthreads();
    const float bz = b2[0];
    const int e0 = j * EPC;
    const int myN = (NE - e0 < EPC) ? (NE - e0) : EPC;

    float ce[4];
    int dd[4], rr[4], ss[4];
#pragma unroll
    for (int k = 0; k < 4; ++k) {
        int p = k * 512 + t;
        dd[k] = -1;
        if (p < myN) {
            int e = e0 + p;
            float a0 = ea[3 * e + 0];
            float a1 = ea[3 * e + 1];
            float a2 = ea[3 * e + 2];
            float c0 = bz, c1 = 0.f, c2 = 0.f, c3 = 0.f;
#pragma unroll
            for (int kk = 0; kk < 64; kk += 4) {
                float h0 = fmaf(a0, sw1[kk+0], fmaf(a1, sw1[64+kk+0], fmaf(a2, sw1[128+kk+0], sb1[kk+0])));
                float h1 = fmaf(a0, sw1[kk+1], fmaf(a1, sw1[64+kk+1], fmaf(a2, sw1[128+kk+1], sb1[kk+1])));
                float h2 = fmaf(a0, sw1[kk+2], fmaf(a1, sw1[64+kk+2], fmaf(a2, sw1[128+kk+2], sb1[kk+2])));
                float h3 = fmaf(a0, sw1[kk+3], fmaf(a1, sw1[64+kk+3], fmaf(a2, sw1[128+kk+3], sb1[kk+3])));
                c0 = fmaf(fmaxf(h0, 0.f), sw2[kk+0], c0);
                c1 = fmaf(fmaxf(h1, 0.f), sw2[kk+1], c1);
                c2 = fmaf(fmaxf(h2, 0.f), sw2[kk+2], c2);
                c3 = fmaf(fmaxf(h3, 0.f), sw2[kk+3], c3);
            }
            ce[k] = (c0 + c1) + (c2 + c3);
            ss[k] = src[e];
            int d = dst[e];
            dd[k] = d;
            rr[k] = atomicAdd(&hist[d >> 8], 1);
        }
    }
    __syncthreads();
    // exclusive scan of hist over 196 buckets (threads 0..255, all barrier)
    int val = 0;
    if (t < 256) { val = (t < NBK) ? hist[t] : 0; part[t] = val; }
    __syncthreads();
    for (int off = 1; off < 256; off <<= 1) {
        int xv = 0, add = 0;
        if (t < 256) { xv = part[t]; if (t >= off) add = part[t - off]; }
        __syncthreads();
        if (t < 256) part[t] = xv + add;
        __syncthreads();
    }
    if (t < NBK) {
        int excl = part[t] - val;
        lexcl[t] = excl;
        ebase[j * NBK + t] = (excl << 16) | val;   // both <= 2048 < 65536
    }
    __syncthreads();
#pragma unroll
    for (int k = 0; k < 4; ++k) {
        if (dd[k] >= 0) {
            int d = dd[k];
            int pos = lexcl[d >> 8] + rr[k];       // dense in [0, myN)
            eLDS[pos] = make_uint2((unsigned)ss[k] | ((unsigned)(d & 255) << 17),
                                   __float_as_uint(ce[k]));
        }
    }
    __syncthreads();
    for (int p = t; p < myN; p += 512)             // linear streaming write
        es[e0 + p] = eLDS[p];
}

// ================= sortround1: gather + dst-sort + round 1 (fused) =========
// Block b gathers bucket b's runs from all 489 chunks (flat index + binary
// search over run bases), counting-sorts by dst&255, writes es2 + nodePtr
// for rounds 2..4, and performs round 1 from the register-held entries.
// h-gathers hoisted into the gather loop so their latency overlaps the scans.
__global__ __launch_bounds__(1024)
void sortround1(const int* __restrict__ ebase,
                const uint2* __restrict__ es,
                uint2* __restrict__ es2,
                uint2* __restrict__ nodePtr,
                const float* __restrict__ hold,
                float* __restrict__ hnew,
                const float* __restrict__ root,
                const float* __restrict__ bias) {
    __shared__ int cbase[NCH + 1];   // exclusive scan of per-chunk run lens
    __shared__ int cex[NCH];         // run offset within each chunk
    __shared__ int hist[256];
    __shared__ int partc[512];       // chunk-scan workspace (489 -> 512)
    __shared__ int part[256];
    __shared__ int cur[256];
    __shared__ float lagg[256];
    const int t = threadIdx.x;
    const int b = blockIdx.x;
    if (t < 256) { hist[t] = 0; lagg[t] = 0.f; }
    // load (excl,cnt) column and scan cnt over 489 chunks
    int c = 0;
    if (t < NCH) {
        int pk = ebase[t * NBK + b];
        cex[t] = pk >> 16;
        c = pk & 0xFFFF;
    }
    if (t < 512) partc[t] = (t < NCH) ? c : 0;
    __syncthreads();
    for (int off = 1; off < 512; off <<= 1) {
        int xv = 0, add = 0;
        if (t < 512) { xv = partc[t]; if (t >= off) add = partc[t - off]; }
        __syncthreads();
        if (t < 512) partc[t] = xv + add;
        __syncthreads();
    }
    if (t < NCH) cbase[t] = partc[t] - c;
    if (t == 0) cbase[NCH] = partc[NCH - 1];       // total C
    __syncthreads();
    const int C = cbase[NCH];                      // <= ~5400; reg slots 6144

    // flat gather into registers + EARLY h-gather (overlaps the scans below)
    uint2 v[6]; float hv[6]; bool m[6];
#pragma unroll
    for (int k = 0; k < 6; ++k) {
        int p = k * 1024 + t;
        m[k] = (p < C);
        if (m[k]) {
            int lo = 0, hi = NCH - 1;              // largest j: cbase[j] <= p
            while (lo < hi) { int mid = (lo + hi + 1) >> 1; if (cbase[mid] <= p) lo = mid; else hi = mid - 1; }
            v[k] = es[lo * EPC + cex[lo] + (p - cbase[lo])];
            atomicAdd(&hist[(v[k].x >> 17) & 255], 1);
            hv[k] = hold[v[k].x & 0x1FFFF];
        }
    }
    __syncthreads();
    // scan hist over 256 node-slots
    int val = 0;
    if (t < 256) { val = hist[t]; part[t] = val; }
    __syncthreads();
    for (int off = 1; off < 256; off <<= 1) {
        int xv = 0, add = 0;
        if (t < 256) { xv = part[t]; if (t >= off) add = part[t - off]; }
        __syncthreads();
        if (t < 256) part[t] = xv + add;
        __syncthreads();
    }
    if (t < 256) {
        int excl = part[t] - val;
        cur[t] = excl;
        int ec = (excl < ESTRIDE) ? excl : ESTRIDE;
        nodePtr[b * 256 + t] = make_uint2((unsigned)(b * ESTRIDE + ec), (unsigned)val);
    }
    __syncthreads();
    // scatter to es2 + round-1 accumulate (h values already in registers)
#pragma unroll
    for (int k = 0; k < 6; ++k) {
        if (m[k]) {
            int key = (v[k].x >> 17) & 255;
            int pos = atomicAdd(&cur[key], 1);
            if (pos < ESTRIDE) es2[b * ESTRIDE + pos] = v[k];
            atomicAdd(&lagg[key], hv[k] * __uint_as_float(v[k].y));
        }
    }
    __syncthreads();
    if (t < 256) {
        int node = b * 256 + t;
        if (node < NN) {
            float inv = (val > 0) ? (1.0f / (float)val) : 0.f;
            hnew[node] = fmaxf(fmaf(hold[node], root[0], fmaf(lagg[t], inv, bias[0])), 0.f);
        }
    }
}

// ================= round_csr: vector-CSR, 8 lanes/row, batched issue ========
// Up to 4 masked es2 loads issued together, then 4 h-gathers, then FMAs.
// Covers deg<=32 (mean 20, sigma 4.5); rare tail loop for deg>32.
__global__ __launch_bounds__(256)
void round_csr(const uint2* __restrict__ nodePtr,
               const uint2* __restrict__ es2,
               const float* __restrict__ hold,
               float* __restrict__ hnew,
               const float* __restrict__ root,
               const float* __restrict__ bias) {
    int g = blockIdx.x * 256 + threadIdx.x;
    int row = g >> 3;
    int sub = g & 7;
    uint2 pk = nodePtr[row];
    int beg = (int)pk.x;
    int len = (int)pk.y;
    bool m0 = (sub      < len), m1 = (sub + 8  < len);
    bool m2 = (sub + 16 < len), m3 = (sub + 24 < len);
    uint2 v0, v1, v2, v3;
    if (m0) v0 = es2[beg + sub];
    if (m1) v1 = es2[beg + sub + 8];
    if (m2) v2 = es2[beg + sub + 16];
    if (m3) v3 = es2[beg + sub + 24];
    float g0 = 0.f, g1 = 0.f, g2 = 0.f, g3 = 0.f;
    if (m0) g0 = hold[v0.x & 0x1FFFF];
    if (m1) g1 = hold[v1.x & 0x1FFFF];
    if (m2) g2 = hold[v2.x & 0x1FFFF];
    if (m3) g3 = hold[v3.x & 0x1FFFF];
    float acc = 0.f;
    if (m0) acc += g0 * __uint_as_float(v0.y);
    if (m1) acc += g1 * __uint_as_float(v1.y);
    if (m2) acc += g2 * __uint_as_float(v2.y);
    if (m3) acc += g3 * __uint_as_float(v3.y);
    for (int k = sub + 32; k < len; k += 8) {      // rare (deg>32: ~0.4%)
        uint2 v = es2[beg + k];
        acc += hold[v.x & 0x1FFFF] * __uint_as_float(v.y);
    }
    acc += __shfl_xor(acc, 1);
    acc += __shfl_xor(acc, 2);
    acc += __shfl_xor(acc, 4);
    if (sub == 0 && row < NN) {
        float inv = (len > 0) ? (1.0f / (float)len) : 0.f;
        hnew[row] = fmaxf(fmaf(hold[row], root[0], fmaf(acc, inv, bias[0])), 0.f);
    }
}

// ================= fallback-path kernels (ws too small) ====================
__global__ void bucket_count(const int* __restrict__ dst, int* __restrict__ bcnt,
                             const float* __restrict__ x, float* __restrict__ h) {
    __shared__ int hist[NBK];
    int t = threadIdx.x;
    if (t < NBK) hist[t] = 0;
    __syncthreads();
    int gid = blockIdx.x * 256 + t;
    if (gid < NN) h[gid] = x[5 * gid + 2];
#pragma unroll
    for (int j = 0; j < 4; ++j) {
        int e = blockIdx.x * EPB + j * 256 + t;
        if (e < NE) atomicAdd(&hist[dst[e] >> 8], 1);
    }
    __syncthreads();
    if (t < NBK && hist[t]) atomicAdd(&bcnt[t], hist[t]);
}

__global__ void bucket_scan(const int* __restrict__ bcnt,
                            int* __restrict__ sBeg,
                            int* __restrict__ cursor,
                            int* __restrict__ sLim) {
    __shared__ int part[256];
    int t = threadIdx.x;
    int v = (t < NBK) ? ((bcnt[t] + 1) & ~1) : 0;   // round up to even
    part[t] = v;
    __syncthreads();
    for (int off = 1; off < 256; off <<= 1) {
        int x = part[t];
        int add = (t >= off) ? part[t - off] : 0;
        __syncthreads();
        part[t] = x + add;
        __syncthreads();
    }
    if (t < NBK) {
        int excl = part[t] - v;
        sBeg[t] = excl;
        cursor[t] = excl;
        sLim[t] = 0x7FFFFFFF;   // exact counts: overflow impossible
    }
}

__global__ void place_kernel(const float* __restrict__ ea,
                             const int* __restrict__ src,
                             const int* __restrict__ dst,
                             const float* __restrict__ w1,
                             const float* __restrict__ b1,
                             const float* __restrict__ w2,
                             const float* __restrict__ b2,
                             const int* __restrict__ sLim,
                             int* __restrict__ cursor,
                             uint2* __restrict__ es,
                             int dumpbase) {
    __shared__ float sw1[192];
    __shared__ float sb1[64];
    __shared__ float sw2[64];
    __shared__ float sce[EPB];
    __shared__ int hist[NBK];
    __shared__ int hbase[NBK];
    int t = threadIdx.x;
    if (t < 192) sw1[t] = w1[t];
    if (t < 64) { sb1[t] = b1[t]; sw2[t] = w2[t]; }
    if (t < NBK) hist[t] = 0;
    __syncthreads();

    int r[4], dd[4];
#pragma unroll
    for (int j = 0; j < 4; ++j) {
        int e = blockIdx.x * EPB + j * 256 + t;
        dd[j] = -1;
        if (e < NE) {
            float a0 = ea[3 * e + 0];
            float a1 = ea[3 * e + 1];
            float a2 = ea[3 * e + 2];
            float c0 = b2[0], c1 = 0.f, c2 = 0.f, c3 = 0.f;
#pragma unroll
            for (int k = 0; k < 64; k += 4) {
                float h0 = fmaf(a0, sw1[k+0], fmaf(a1, sw1[64+k+0], fmaf(a2, sw1[128+k+0], sb1[k+0])));
                float h1 = fmaf(a0, sw1[k+1], fmaf(a1, sw1[64+k+1], fmaf(a2, sw1[128+k+1], sb1[k+1])));
                float h2 = fmaf(a0, sw1[k+2], fmaf(a1, sw1[64+k+2], fmaf(a2, sw1[128+k+2], sb1[k+2])));
                float h3 = fmaf(a0, sw1[k+3], fmaf(a1, sw1[64+k+3], fmaf(a2, sw1[128+k+3], sb1[k+3])));
                c0 = fmaf(fmaxf(h0, 0.f), sw2[k+0], c0);
                c1 = fmaf(fmaxf(h1, 0.f), sw2[k+1], c1);
                c2 = fmaf(fmaxf(h2, 0.f), sw2[k+2], c2);
                c3 = fmaf(fmaxf(h3, 0.f), sw2[k+3], c3);
            }
            sce[j * 256 + t] = (c0 + c1) + (c2 + c3);
            int d = dst[e];
            dd[j] = d;
            r[j] = atomicAdd(&hist[d >> 8], 1);
        }
    }
    __syncthreads();
    if (t < NBK) { int hv = hist[t]; if (hv) hbase[t] = atomicAdd(&cursor[t], hv); }
    __syncthreads();
#pragma unroll
    for (int j = 0; j < 4; ++j) {
        int e = blockIdx.x * EPB + j * 256 + t;
        if (e < NE) {
            int d = dd[j];
            int b = d >> 8;
            int pos = hbase[b] + r[j];
            if (pos >= sLim[b]) pos = dumpbase + (t & 63);
            unsigned pack = (unsigned)src[e] | ((unsigned)(d & 255) << 17);
            es[pos] = make_uint2(pack, __float_as_uint(sce[j * 256 + t]));
        }
    }
}

template<int FIRST>
__global__ __launch_bounds__(1024)
void round_fused_fb(const int* __restrict__ sBeg,
                    const int* __restrict__ sEnd,
                    const int* __restrict__ sLim,
                    const uint2* __restrict__ es,
                    const float* __restrict__ hold,
                    float* __restrict__ hnew,
                    float* __restrict__ invdeg,
                    const float* __restrict__ root,
                    const float* __restrict__ bias) {
    __shared__ float lagg[256];
    __shared__ int ldeg[256];
    int t = threadIdx.x;
    int b = blockIdx.x;
    if (t < 256) { lagg[t] = 0.f; if (FIRST) ldeg[t] = 0; }
    __syncthreads();
    int s0 = sBeg[b];
    int s1 = sEnd[b];
    { int cap = sLim[b]; if (s1 > cap) s1 = cap; }
    const uint4* es4 = (const uint4*)es;
    for (int p = s0 + t * 2; p < s1; p += 2048) {
        uint4 v = es4[p >> 1];
        {
            int sidx = v.x & 0x1FFFF;
            int dl = (v.x >> 17) & 255;
            atomicAdd(&lagg[dl], hold[sidx] * __uint_as_float(v.y));
            if (FIRST) atomicAdd(&ldeg[dl], 1);
        }
        if (p + 1 < s1) {
            int sidx = v.z & 0x1FFFF;
            int dl = (v.z >> 17) & 255;
            atomicAdd(&lagg[dl], hold[sidx] * __uint_as_float(v.w));
            if (FIRST) atomicAdd(&ldeg[dl], 1);
        }
    }
    __syncthreads();
    if (t < 256) {
        int node = b * 256 + t;
        if (node < NN) {
            float inv;
            if (FIRST) {
                int d = ldeg[t];
                inv = (d > 0) ? (1.0f / (float)d) : 0.f;
                invdeg[node] = inv;
            } else {
                inv = invdeg[node];
            }
            hnew[node] = fmaxf(fmaf(hold[node], root[0], fmaf(lagg[t], inv, bias[0])), 0.f);
        }
    }
}

// ================= launch =================

extern "C" void kernel_launch(void* const* d_in, const int* in_sizes, int n_in,
                              void* d_out, int out_size, void* d_ws, size_t ws_size,
                              hipStream_t stream) {
    const float* x    = (const float*)d_in[0];
    const int*   ei   = (const int*)d_in[1];
    const float* ea   = (const float*)d_in[2];
    const float* w1   = (const float*)d_in[3];
    const float* b1   = (const float*)d_in[4];
    const float* w2   = (const float*)d_in[5];
    const float* b2   = (const float*)d_in[6];
    const float* root = (const float*)d_in[7];
    const float* bias = (const float*)d_in[8];

    const int* src = ei;
    const int* dst = ei + NE;
    float* out = (float*)d_out;

    const size_t esN  = (size_t)NCH * EPC;                // chunked es (dense)
    const size_t es2N = (size_t)NBK * ESTRIDE + 64;       // sorted es2 + dump
    const size_t needFixed = esN * 8 + es2N * 8
                           + (size_t)(NCH * NBK) * 4      // ebase
                           + (size_t)NNP * 8              // nodePtr
                           + (size_t)NN * 4 * 2;          // hA, hB

    if (ws_size >= needFixed) {
        // -------- fixed path: 5 dispatches, no memset --------
        uint2* es      = (uint2*)d_ws;
        uint2* es2     = es + esN;
        int*   ebase   = (int*)(es2 + es2N);
        uint2* nodePtr = (uint2*)(ebase + (size_t)NCH * NBK);
        float* hA      = (float*)(nodePtr + NNP);
        float* hB      = hA + NN;

        place4<<<NCH, 512, 0, stream>>>(x, ea, src, dst, w1, b1, w2, b2,
                                        es, ebase, hA);
        sortround1<<<NBK, 1024, 0, stream>>>(ebase, es, es2, nodePtr,
                                             hA, hB, root, bias);
        const int gR = NNP * 8 / 256;    // 1568 blocks, 8 lanes/row
        round_csr<<<gR, 256, 0, stream>>>(nodePtr, es2, hB, hA, root, bias);
        round_csr<<<gR, 256, 0, stream>>>(nodePtr, es2, hA, hB, root, bias);
        round_csr<<<gR, 256, 0, stream>>>(nodePtr, es2, hB, out, root, bias);
    } else {
        // -------- fallback: exact counts via count+scan --------
        uint2* es     = (uint2*)d_ws;                    // NE + NBK entries
        int*   bcnt   = (int*)(es + NE + NBK);
        int*   cursor = bcnt + NBK;
        int*   sBeg   = cursor + NBK;
        int*   sLim   = sBeg + NBK;
        float* invdeg = (float*)(sLim + NBK);
        float* hB     = invdeg + NN;
        float* h      = out;

        hipMemsetAsync(bcnt, 0, NBK * 4, stream);
        bucket_count<<<PB, 256, 0, stream>>>(dst, bcnt, x, h);
        bucket_scan<<<1, 256, 0, stream>>>(bcnt, sBeg, cursor, sLim);
        place_kernel<<<PB, 256, 0, stream>>>(ea, src, dst, w1, b1, w2, b2,
                                             sLim, cursor, es, 0);
        round_fused_fb<1><<<NBK, 1024, 0, stream>>>(sBeg, cursor, sLim, es, h,  hB, invdeg, root, bias);
        round_fused_fb<0><<<NBK, 1024, 0, stream>>>(sBeg, cursor, sLim, es, hB, h,  invdeg, root, bias);
        round_fused_fb<0><<<NBK, 1024, 0, stream>>>(sBeg, cursor, sLim, es, h,  hB, invdeg, root, bias);
        round_fused_fb<0><<<NBK, 1024, 0, stream>>>(sBeg, cursor, sLim, es, hB, h,  invdeg, root, bias);
    }
}